// Round 10
// baseline (130.835 us; speedup 1.0000x reference)
//
#include <hip/hip_runtime.h>
#include <hip/hip_bf16.h>

#define NB 1024
#define NH 256
#define EMB 128
#define TWOD 256
#define HID 256
#define ROWS 128            // history rows per block
#define BPB 2               // blocks per batch element
#define NBLK (NB * BPB)

typedef __attribute__((ext_vector_type(4))) float f32x4;
typedef __attribute__((ext_vector_type(8))) short bf16x8;

__device__ __forceinline__ unsigned short f2bf(float f) {
  union { float f; unsigned u; } v; v.f = f;
  unsigned u = v.u;
  unsigned r = (u + 0x7fffu + ((u >> 16) & 1u)) >> 16;
  return (unsigned short)r;
}

__device__ __forceinline__ float bf2f(short s) {
  union { unsigned u; float f; } c;
  c.u = ((unsigned)(unsigned short)s) << 16;
  return c.f;
}

__device__ __forceinline__ bf16x8 pack8(f32x4 a, f32x4 b) {
  union { bf16x8 w; unsigned u[4]; } r;
  float2 p;
  union { __hip_bfloat162 h; unsigned u; } c;
  p.x = a[0]; p.y = a[1]; c.h = __float22bfloat162_rn(p); r.u[0] = c.u;
  p.x = a[2]; p.y = a[3]; c.h = __float22bfloat162_rn(p); r.u[1] = c.u;
  p.x = b[0]; p.y = b[1]; c.h = __float22bfloat162_rn(p); r.u[2] = c.u;
  p.x = b[2]; p.y = b[3]; c.h = __float22bfloat162_rn(p); r.u[3] = c.u;
  return r.w;
}

// W1 [d=256][n=256] fp32 -> W1T [n][d] bf16 (B-fragment: n-major, k contiguous)
__global__ __launch_bounds__(256) void prep_w1t(const float* __restrict__ W1,
                                                unsigned short* __restrict__ W1T) {
  const int d = blockIdx.x;
  const int n = threadIdx.x;
  W1T[(size_t)n * TWOD + d] = f2bf(W1[(size_t)d * HID + n]);
}

// 2048 blocks (2 per b), 512 threads = 8 waves, 128 rows per block.
// Key structure vs round 8:
//  - tgt folded into B (W1b = diag(tgt)@W1): A-panels are RAW embedding rows,
//    gathered fp32 (coalesced, 32 lanes/row) + cvt -> no prep_ebf, no fold pass.
//  - wave's 16 folded W1b fragments pinned in AGPRs (opaque asm, class 'a'):
//    the kk-loop has ZERO global loads (pure ds_read + MFMA).
//  - dot_ht via ones-column MFMA (B-frag = tgt) on wave 0 only.
__global__ __launch_bounds__(512, 2) void nais_main(
    const int* __restrict__ history, const int* __restrict__ target,
    const int* __restrict__ hregion, const int* __restrict__ tregion,
    const float* __restrict__ E_hist, const float* __restrict__ E_targ,
    const float* __restrict__ E_reg,
    const unsigned short* __restrict__ W1T, const float* __restrict__ b1,
    const float* __restrict__ w2,
    float* __restrict__ part_se, float* __restrict__ part_sd)
{
  const int blk = blockIdx.x;
  const int b = blk >> 1;
  const int r0 = (blk & 1) * ROWS;
  const int tid = threadIdx.x;
  const int lane = tid & 63;
  const int wave = tid >> 6;            // 0..7
  const int l15 = lane & 15;
  const int lhi = lane >> 4;
  const int l31 = lane & 31;
  const int halfsel = lane >> 5;        // 0: E_hist half, 1: E_reg half

  __shared__ __align__(16) unsigned short A_h[ROWS * EMB];   // 32 KiB raw bf16
  __shared__ __align__(16) unsigned short A_r[ROWS * EMB];   // 32 KiB raw bf16
  __shared__ __align__(16) float tgt_lds[TWOD];
  __shared__ __align__(16) unsigned short tgtbf[TWOD];
  __shared__ int keys_h[ROWS];
  __shared__ int keys_r[ROWS];
  __shared__ float dot_lds[ROWS];
  __shared__ float score_parts[8][ROWS];

  const int tgt_item = target[b];

  // ---- P0: keys + target vector (f32 + bf16) ----
  if (tid < ROWS) {
    keys_h[tid] = history[b * NH + r0 + tid];
  } else if (tid < 2 * ROWS) {
    keys_r[tid - ROWS] = hregion[b * NH + r0 + (tid - ROWS)];
  } else {
    const int c = tid - 2 * ROWS;       // 0..255
    const float v = (c < EMB) ? E_targ[(size_t)target[b] * EMB + c]
                              : E_reg[(size_t)tregion[b] * EMB + (c - EMB)];
    tgt_lds[c] = v;
    tgtbf[c] = f2bf(v);
  }
  __syncthreads();

  // ---- P1: coalesced fp32 register gather -> cvt -> swizzled raw panels ----
  {
    const float* table = halfsel ? E_reg : E_hist;
    const int* keys = halfsel ? keys_r : keys_h;
    unsigned short* panel = halfsel ? A_r : A_h;
    #pragma unroll
    for (int pass = 0; pass < 2; ++pass) {
      int key[8];
      #pragma unroll
      for (int s = 0; s < 8; ++s)
        key[s] = keys[wave * 16 + pass * 8 + s];
      f32x4 vb[8];
      #pragma unroll
      for (int s = 0; s < 8; ++s)
        vb[s] = *(const f32x4*)(table + (size_t)key[s] * EMB + l31 * 4);
      #pragma unroll
      for (int s = 0; s < 8; ++s) {
        const int row = wave * 16 + pass * 8 + s;
        float2 f01; f01.x = vb[s][0]; f01.y = vb[s][1];
        float2 f23; f23.x = vb[s][2]; f23.y = vb[s][3];
        union { __hip_bfloat162 h; unsigned u; } c0, c1;
        c0.h = __float22bfloat162_rn(f01);
        c1.h = __float22bfloat162_rn(f23);
        const int g = l31 >> 1;                 // granule 0..15 within row
        const int gs = g ^ (row & 7);           // XOR swizzle (involution)
        unsigned* dst = (unsigned*)&panel[row * EMB + gs * 8] + (l31 & 1) * 2;
        dst[0] = c0.u; dst[1] = c1.u;
      }
    }
  }

  // ---- bfr setup: load W1T strip, fold tgt (W1b = diag(tgt)@W1), pin AGPR.
  //      Overlaps the in-flight gather above; reads tgt_lds (sync'd by P0 bar).
  const int col0 = wave * 32;
  bf16x8 bfr[8][2];
  #pragma unroll
  for (int kk = 0; kk < 8; ++kk) {
    const f32x4 t0 = *(const f32x4*)&tgt_lds[kk * 32 + lhi * 8];
    const f32x4 t1 = *(const f32x4*)&tgt_lds[kk * 32 + lhi * 8 + 4];
    #pragma unroll
    for (int n = 0; n < 2; ++n) {
      const bf16x8 w = *(const bf16x8*)(W1T + (size_t)(col0 + n * 16 + l15) * TWOD + kk * 32 + lhi * 8);
      f32x4 lo, hi;
      #pragma unroll
      for (int e = 0; e < 4; ++e) {
        lo[e] = bf2f(w[e]) * t0[e];
        hi[e] = bf2f(w[4 + e]) * t1[e];
      }
      bfr[kk][n] = pack8(lo, hi);
      asm volatile("" : "+a"(bfr[kk][n]));   // pin to AGPR, non-rematerializable
    }
  }
  float b1v[2], w2v[2];
  #pragma unroll
  for (int n = 0; n < 2; ++n) {
    b1v[n] = b1[col0 + n * 16 + l15];
    w2v[n] = w2[col0 + n * 16 + l15];
  }
  __syncthreads();

  // ---- P2: GEMM. kk outer; per kk: 8 ds_read + 16 MFMA, bfr from AGPR ----
  f32x4 acc[2][4][2];
  f32x4 acc2[2][4];                      // ones-column (dot), wave 0 only
  #pragma unroll
  for (int c = 0; c < 2; ++c)
    #pragma unroll
    for (int m = 0; m < 4; ++m) {
      acc2[c][m] = (f32x4){0.f, 0.f, 0.f, 0.f};
      #pragma unroll
      for (int n = 0; n < 2; ++n)
        acc[c][m][n] = (f32x4){0.f, 0.f, 0.f, 0.f};
    }

  #pragma unroll
  for (int kk = 0; kk < 8; ++kk) {
    const unsigned short* panel = (kk < 4) ? A_h : A_r;
    bf16x8 af[2][4];
    #pragma unroll
    for (int c = 0; c < 2; ++c)
      #pragma unroll
      for (int m = 0; m < 4; ++m) {
        const int row = c * 64 + m * 16 + l15;
        const int gk = ((kk & 3) * 4 + lhi) ^ (row & 7);
        af[c][m] = *(const bf16x8*)&panel[row * EMB + gk * 8];
      }
    __builtin_amdgcn_s_setprio(1);
    #pragma unroll
    for (int c = 0; c < 2; ++c)
      #pragma unroll
      for (int m = 0; m < 4; ++m)
        #pragma unroll
        for (int n = 0; n < 2; ++n)
          acc[c][m][n] = __builtin_amdgcn_mfma_f32_16x16x32_bf16(af[c][m], bfr[kk][n], acc[c][m][n], 0, 0, 0);
    __builtin_amdgcn_s_setprio(0);
    if (wave == 0) {                      // dot = hist . tgt via ones-column
      const bf16x8 tfr = *(const bf16x8*)&tgtbf[kk * 32 + lhi * 8];
      #pragma unroll
      for (int c = 0; c < 2; ++c)
        #pragma unroll
        for (int m = 0; m < 4; ++m)
          acc2[c][m] = __builtin_amdgcn_mfma_f32_16x16x32_bf16(af[c][m], tfr, acc2[c][m], 0, 0, 0);
    }
  }

  // wave 0: extract dot (same value in every l15 column; use col 0 lanes)
  if (wave == 0 && l15 == 0) {
    #pragma unroll
    for (int c = 0; c < 2; ++c)
      #pragma unroll
      for (int m = 0; m < 4; ++m)
        #pragma unroll
        for (int r = 0; r < 4; ++r)
          dot_lds[c * 64 + m * 16 + lhi * 4 + r] = acc2[c][m][r];
  }

  // ---- epilogue: relu + b1, dot w2, 16-lane reduce -> score_parts ----
  #pragma unroll
  for (int c = 0; c < 2; ++c) {
    #pragma unroll
    for (int m = 0; m < 4; ++m) {
      #pragma unroll
      for (int r = 0; r < 4; ++r) {
        float p = 0.f;
        #pragma unroll
        for (int n = 0; n < 2; ++n) {
          float hv = acc[c][m][n][r] + b1v[n];  // C/D: col=lane&15, row=(lane>>4)*4+r
          hv = hv > 0.f ? hv : 0.f;
          p += hv * w2v[n];
        }
        p += __shfl_xor(p, 1);
        p += __shfl_xor(p, 2);
        p += __shfl_xor(p, 4);
        p += __shfl_xor(p, 8);
        if (l15 == 0) score_parts[wave][c * 64 + m * 16 + lhi * 4 + r] = p;
      }
    }
  }
  __syncthreads();

  // ---- P3: masked exp + partial sums -> per-(block,wave) ws slots ----
  if (wave < 2) {
    const int lrow = wave * 64 + lane;
    float sc = 0.f;
    #pragma unroll
    for (int w = 0; w < 8; ++w) sc += score_parts[w][lrow];
    float e = (keys_h[lrow] != tgt_item) ? expf(sc) : 0.f;
    float ed = e * dot_lds[lrow];
    #pragma unroll
    for (int off = 32; off >= 1; off >>= 1) {
      e += __shfl_xor(e, off);
      ed += __shfl_xor(ed, off);
    }
    if (lane == 0) {
      part_se[blk * 2 + wave] = e;
      part_sd[blk * 2 + wave] = ed;
    }
  }
}

__global__ __launch_bounds__(256) void finalize(const float* __restrict__ part_se,
                                                const float* __restrict__ part_sd,
                                                float* __restrict__ out) {
  const int b = blockIdx.x * 256 + threadIdx.x;
  if (b < NB) {
    float se = 0.f, sd = 0.f;
    #pragma unroll
    for (int i = 0; i < BPB * 2; ++i) {
      se += part_se[b * BPB * 2 + i];
      sd += part_sd[b * BPB * 2 + i];
    }
    const float pred = (se > 0.f) ? (sd / sqrtf(se)) : 0.f;  // denom = sum^0.5
    out[b] = 1.f / (1.f + expf(-pred));
  }
}

extern "C" void kernel_launch(void* const* d_in, const int* in_sizes, int n_in,
                              void* d_out, int out_size, void* d_ws, size_t ws_size,
                              hipStream_t stream) {
  const int* history = (const int*)d_in[0];
  const int* target  = (const int*)d_in[1];
  const int* hregion = (const int*)d_in[2];
  const int* tregion = (const int*)d_in[3];
  const float* E_hist = (const float*)d_in[4];
  const float* E_targ = (const float*)d_in[5];
  const float* E_reg  = (const float*)d_in[6];
  const float* W1 = (const float*)d_in[7];
  const float* b1 = (const float*)d_in[8];
  const float* w2 = (const float*)d_in[9];
  float* out = (float*)d_out;

  char* p = (char*)d_ws;
  unsigned short* W1T = (unsigned short*)p;  p += (size_t)TWOD * HID * 2;   // 128 KB
  float* part_se = (float*)p;                p += (size_t)NBLK * 2 * 4;     // 16 KB
  float* part_sd = (float*)p;

  prep_w1t<<<TWOD, HID, 0, stream>>>(W1, W1T);
  nais_main<<<NBLK, 512, 0, stream>>>(history, target, hregion, tregion,
                                      E_hist, E_targ, E_reg, W1T, b1, w2,
                                      part_se, part_sd);
  finalize<<<(NB + 255) / 256, 256, 0, stream>>>(part_se, part_sd, out);
}